// Round 1
// baseline (2819.608 us; speedup 1.0000x reference)
//
#include <hip/hip_runtime.h>
#include <hip/hip_bf16.h>

// Problem constants (from reference):
//   N_NODES=100000, N_EDGES=1600000, D_IN=D_OUT=128
// out = segment_sum(x[edge_col] * edge_vals[:,None], edge_row) @ weight
//
// d_in order: 0=x[f32 N*128], 1=edge_row[i32 E], 2=edge_col[i32 E],
//             3=edge_vals[f32 E], 4=weight[f32 128*128]
// d_out: f32 N*128
// d_ws: agg buffer, N*128*4 = 51.2 MB (re-poisoned every call -> zero it here)

#define N_NODES 100000
#define N_EDGES 1600000
#define DIM     128

// ---------------------------------------------------------------- zero agg
__global__ __launch_bounds__(256) void zero_kernel(float4* p, int n4) {
    int i = blockIdx.x * 256 + threadIdx.x;
    if (i < n4) p[i] = make_float4(0.f, 0.f, 0.f, 0.f);
}

// ---------------------------------------------------------------- scatter
// one thread per (edge, feature-quad): 32 quads of float4 cover 128 feats
__global__ __launch_bounds__(256) void scatter_kernel(
    const float4* __restrict__ x4,
    const int*    __restrict__ erow,
    const int*    __restrict__ ecol,
    const float*  __restrict__ eval,
    float*        __restrict__ agg)
{
    unsigned tid = blockIdx.x * 256u + threadIdx.x;   // < E*32 = 51.2M
    unsigned e = tid >> 5;
    unsigned q = tid & 31u;
    int c = ecol[e];
    int r = erow[e];
    float v = eval[e];
    float4 xv = x4[(size_t)c * 32u + q];
    float* dst = agg + (size_t)r * 128u + q * 4u;
    atomicAdd(dst + 0, xv.x * v);
    atomicAdd(dst + 1, xv.y * v);
    atomicAdd(dst + 2, xv.z * v);
    atomicAdd(dst + 3, xv.w * v);
}

// ---------------------------------------------------------------- GEMM
// out[N,128] = agg[N,128] @ W[128,128], fp32 vector ALU.
// Block: 256 threads, tile = 32 rows x 128 cols, K staged in chunks of 32.
// Thread micro-tile: 4 rows x 4 cols (acc[4][4]).
__global__ __launch_bounds__(256) void gemm_kernel(
    const float* __restrict__ agg,
    const float* __restrict__ W,
    float*       __restrict__ out)
{
    __shared__ float As[32 * 32];     // [row][kk]  4 KB
    __shared__ float Ws[32 * 128];    // [kk][col] 16 KB

    const int t    = threadIdx.x;
    const int row0 = blockIdx.x * 32;          // 100000/32 = 3125 blocks exact
    const int r0   = (t >> 5) * 4;             // 0..28
    const int c0   = (t & 31) * 4;             // 0..124

    float acc[4][4];
#pragma unroll
    for (int i = 0; i < 4; ++i)
#pragma unroll
        for (int j = 0; j < 4; ++j) acc[i][j] = 0.f;

    for (int k0 = 0; k0 < 128; k0 += 32) {
        // stage A chunk: 32 rows x 32 k = 256 float4, 1 per thread
        {
            int r  = t >> 3;          // 0..31
            int kp = t & 7;           // 0..7 (float4 index)
            float4 a = *(const float4*)(agg + (size_t)(row0 + r) * 128 + k0 + kp * 4);
            *(float4*)(As + r * 32 + kp * 4) = a;
        }
        // stage W chunk: 32 k x 128 cols = 1024 float4, 4 per thread
        {
            const float4* Wg = (const float4*)(W + (size_t)k0 * 128);
            float4* Wl = (float4*)Ws;
#pragma unroll
            for (int i = 0; i < 4; ++i) Wl[t + 256 * i] = Wg[t + 256 * i];
        }
        __syncthreads();

#pragma unroll
        for (int kk = 0; kk < 32; ++kk) {
            float4 w = *(const float4*)(Ws + kk * 128 + c0);
            float a0 = As[(r0 + 0) * 32 + kk];
            float a1 = As[(r0 + 1) * 32 + kk];
            float a2 = As[(r0 + 2) * 32 + kk];
            float a3 = As[(r0 + 3) * 32 + kk];
            acc[0][0] += a0 * w.x; acc[0][1] += a0 * w.y; acc[0][2] += a0 * w.z; acc[0][3] += a0 * w.w;
            acc[1][0] += a1 * w.x; acc[1][1] += a1 * w.y; acc[1][2] += a1 * w.z; acc[1][3] += a1 * w.w;
            acc[2][0] += a2 * w.x; acc[2][1] += a2 * w.y; acc[2][2] += a2 * w.z; acc[2][3] += a2 * w.w;
            acc[3][0] += a3 * w.x; acc[3][1] += a3 * w.y; acc[3][2] += a3 * w.z; acc[3][3] += a3 * w.w;
        }
        __syncthreads();
    }

#pragma unroll
    for (int i = 0; i < 4; ++i) {
        float4 o = make_float4(acc[i][0], acc[i][1], acc[i][2], acc[i][3]);
        *(float4*)(out + (size_t)(row0 + r0 + i) * 128 + c0) = o;
    }
}

// ---------------------------------------------------------------- launch
extern "C" void kernel_launch(void* const* d_in, const int* in_sizes, int n_in,
                              void* d_out, int out_size, void* d_ws, size_t ws_size,
                              hipStream_t stream) {
    const float* x    = (const float*)d_in[0];
    const int*   erow = (const int*)d_in[1];
    const int*   ecol = (const int*)d_in[2];
    const float* eval = (const float*)d_in[3];
    const float* W    = (const float*)d_in[4];
    float* out = (float*)d_out;
    float* agg = (float*)d_ws;   // needs N*128*4 = 51.2 MB

    // 1) zero agg (ws is poisoned 0xAA before every call)
    {
        int n4 = N_NODES * DIM / 4;               // 3,200,000
        zero_kernel<<<n4 / 256, 256, 0, stream>>>((float4*)agg, n4);
    }
    // 2) scatter: E*32 threads
    {
        unsigned total = (unsigned)N_EDGES * 32u; // 51.2M, /256 = 200000 blocks
        scatter_kernel<<<total / 256, 256, 0, stream>>>(
            (const float4*)x, erow, ecol, eval, agg);
    }
    // 3) GEMM
    gemm_kernel<<<N_NODES / 32, 256, 0, stream>>>(agg, W, out);
}

// Round 2
// 1570.399 us; speedup vs baseline: 1.7955x; 1.7955x over previous
//
#include <hip/hip_runtime.h>
#include <hip/hip_bf16.h>

// out = segment_sum(x[edge_col] * edge_vals[:,None], edge_row) @ W
// N=100000, E=1600000, D=128.
//
// Strategy (R2): counting-sort edges into 3125 buckets of 32 dst rows each,
// then one block per bucket accumulates into LDS (ds_add_f32, conflict-free
// stride-32 layout) and runs the 32x128 @ 128x128 GEMM in-place, writing out
// directly. Eliminates all global fp32 atomics (R1: 3.28 GB atomic
// write-through = 95% of runtime).

#define N_NODES 100000
#define N_EDGES 1600000
#define DIM     128
#define NBUCK   3125          // N_NODES / 32

// ---- workspace layout (bytes) ----
// cnt    : ws + 0        , 3200 u32
// start  : ws + 12800    , 3200 u32
// cursor : ws + 25600    , 3200 u32
// ebuf   : ws + 65536    , E * 8 B  (uint2: {rowLocal<<17|col, f32 bits})

// ---------------------------------------------------------------- zero cnt
__global__ __launch_bounds__(256) void zero_cnt_kernel(unsigned* cnt) {
    int i = blockIdx.x * 256 + threadIdx.x;
    if (i < NBUCK) cnt[i] = 0u;
}

// ---------------------------------------------------------------- histogram
__global__ __launch_bounds__(256) void hist_kernel(
    const int* __restrict__ erow, unsigned* __restrict__ cnt)
{
    int e = blockIdx.x * 256 + threadIdx.x;       // grid exact: E/256
    atomicAdd(&cnt[(unsigned)erow[e] >> 5], 1u);
}

// ---------------------------------------------------------------- scan
// exclusive prefix over NBUCK counters, single block of 1024 threads
__global__ __launch_bounds__(1024) void scan_kernel(
    const unsigned* __restrict__ cnt,
    unsigned* __restrict__ start,
    unsigned* __restrict__ cursor)
{
    __shared__ unsigned wsum[16];
    const int t = threadIdx.x;
    const int base = t * 4;
    unsigned v[4];
    unsigned s = 0;
#pragma unroll
    for (int k = 0; k < 4; ++k) {
        v[k] = (base + k < NBUCK) ? cnt[base + k] : 0u;
        s += v[k];
    }
    // inclusive wave scan of s (wave64)
    unsigned inc = s;
#pragma unroll
    for (int d = 1; d < 64; d <<= 1) {
        unsigned o = __shfl_up(inc, d);
        if ((t & 63) >= d) inc += o;
    }
    if ((t & 63) == 63) wsum[t >> 6] = inc;
    __syncthreads();
    if (t == 0) {
        unsigned run = 0;
#pragma unroll
        for (int i = 0; i < 16; ++i) { unsigned w = wsum[i]; wsum[i] = run; run += w; }
    }
    __syncthreads();
    unsigned excl = inc - s + wsum[t >> 6];
#pragma unroll
    for (int k = 0; k < 4; ++k) {
        if (base + k < NBUCK) { start[base + k] = excl; cursor[base + k] = excl; }
        excl += v[k];
    }
}

// ---------------------------------------------------------------- placement
__global__ __launch_bounds__(256) void place_kernel(
    const int*   __restrict__ erow,
    const int*   __restrict__ ecol,
    const float* __restrict__ eval,
    unsigned*    __restrict__ cursor,
    uint2*       __restrict__ ebuf)
{
    int e = blockIdx.x * 256 + threadIdx.x;       // grid exact
    unsigned r = (unsigned)erow[e];
    unsigned b = r >> 5;
    unsigned pos = atomicAdd(&cursor[b], 1u);
    ebuf[pos] = make_uint2(((r & 31u) << 17) | (unsigned)ecol[e],
                           __float_as_uint(eval[e]));
}

// ---------------------------------------------------------------- fused
// one block per bucket: LDS segmented-sum of its edges, then GEMM, write out.
__global__ __launch_bounds__(256) void fused_kernel(
    const float*    __restrict__ x,
    const float*    __restrict__ W,
    const unsigned* __restrict__ cnt,
    const unsigned* __restrict__ start,
    const uint2*    __restrict__ ebuf,
    float*          __restrict__ out)
{
    __shared__ float acc[32 * 132];   // 32 rows, +4 word pad -> conflict-free
    __shared__ float Ws[32 * 128];    // staged W chunk

    const int t = threadIdx.x;
    const int b = blockIdx.x;

    // zero accumulator tile
    for (int i = t; i < 32 * 132; i += 256) acc[i] = 0.f;
    __syncthreads();

    const unsigned n  = cnt[b];
    const unsigned s0 = start[b];
    const int g = t >> 5;             // edge slot within batch of 8
    const int q = t & 31;             // feature lane

    for (unsigned i = g; i < n; i += 8) {
        uint2 ev = ebuf[s0 + i];                       // broadcast within half-wave
        unsigned col = ev.x & 0x1FFFFu;
        unsigned rl  = ev.x >> 17;
        float val = __uint_as_float(ev.y);
        const float* xp = x + (size_t)col * DIM + q;
        float f0 = xp[0]  * val;
        float f1 = xp[32] * val;
        float f2 = xp[64] * val;
        float f3 = xp[96] * val;
        float* ap = acc + rl * 132 + q;
        atomicAdd(ap +  0, f0);   // banks (4*rl + q) % 32: lanes distinct
        atomicAdd(ap + 32, f1);
        atomicAdd(ap + 64, f2);
        atomicAdd(ap + 96, f3);
    }
    __syncthreads();

    // GEMM: out[32,128] = acc[32,128] @ W[128,128]
    const int r0 = (t >> 5) * 4;      // 0..28
    const int c0 = (t & 31) * 4;      // 0..124
    float4 o[4];
#pragma unroll
    for (int i = 0; i < 4; ++i) o[i] = make_float4(0.f, 0.f, 0.f, 0.f);

    for (int k0 = 0; k0 < 128; k0 += 32) {
        // stage W chunk 32x128 (1024 float4, 4 per thread)
        {
            const float4* Wg = (const float4*)(W + (size_t)k0 * DIM);
            float4* Wl = (float4*)Ws;
#pragma unroll
            for (int i = 0; i < 4; ++i) Wl[t + 256 * i] = Wg[t + 256 * i];
        }
        __syncthreads();

#pragma unroll
        for (int kk = 0; kk < 32; kk += 4) {
            float4 a0 = *(const float4*)(acc + (r0 + 0) * 132 + k0 + kk);
            float4 a1 = *(const float4*)(acc + (r0 + 1) * 132 + k0 + kk);
            float4 a2 = *(const float4*)(acc + (r0 + 2) * 132 + k0 + kk);
            float4 a3 = *(const float4*)(acc + (r0 + 3) * 132 + k0 + kk);
            float4 w0 = *(const float4*)(Ws + (kk + 0) * DIM + c0);
            float4 w1 = *(const float4*)(Ws + (kk + 1) * DIM + c0);
            float4 w2 = *(const float4*)(Ws + (kk + 2) * DIM + c0);
            float4 w3 = *(const float4*)(Ws + (kk + 3) * DIM + c0);
#define FMA4(oi, ai)                                                         \
            oi.x += ai.x * w0.x + ai.y * w1.x + ai.z * w2.x + ai.w * w3.x;   \
            oi.y += ai.x * w0.y + ai.y * w1.y + ai.z * w2.y + ai.w * w3.y;   \
            oi.z += ai.x * w0.z + ai.y * w1.z + ai.z * w2.z + ai.w * w3.z;   \
            oi.w += ai.x * w0.w + ai.y * w1.w + ai.z * w2.w + ai.w * w3.w;
            FMA4(o[0], a0) FMA4(o[1], a1) FMA4(o[2], a2) FMA4(o[3], a3)
#undef FMA4
        }
        __syncthreads();
    }

#pragma unroll
    for (int i = 0; i < 4; ++i)
        *(float4*)(out + (size_t)(b * 32 + r0 + i) * DIM + c0) = o[i];
}

// ---------------------------------------------------------------- launch
extern "C" void kernel_launch(void* const* d_in, const int* in_sizes, int n_in,
                              void* d_out, int out_size, void* d_ws, size_t ws_size,
                              hipStream_t stream) {
    const float* x    = (const float*)d_in[0];
    const int*   erow = (const int*)d_in[1];
    const int*   ecol = (const int*)d_in[2];
    const float* eval = (const float*)d_in[3];
    const float* W    = (const float*)d_in[4];
    float* out = (float*)d_out;

    char* ws = (char*)d_ws;
    unsigned* cnt    = (unsigned*)(ws + 0);
    unsigned* start  = (unsigned*)(ws + 12800);
    unsigned* cursor = (unsigned*)(ws + 25600);
    uint2*    ebuf   = (uint2*)   (ws + 65536);   // 12.8 MB

    zero_cnt_kernel<<<(NBUCK + 255) / 256, 256, 0, stream>>>(cnt);
    hist_kernel<<<N_EDGES / 256, 256, 0, stream>>>(erow, cnt);
    scan_kernel<<<1, 1024, 0, stream>>>(cnt, start, cursor);
    place_kernel<<<N_EDGES / 256, 256, 0, stream>>>(erow, ecol, eval, cursor, ebuf);
    fused_kernel<<<NBUCK, 256, 0, stream>>>(x, W, cnt, start, ebuf, out);
}

// Round 3
// 616.029 us; speedup vs baseline: 4.5771x; 2.5492x over previous
//
#include <hip/hip_runtime.h>
#include <hip/hip_bf16.h>

// out = segment_sum(x[edge_col] * edge_vals[:,None], edge_row) @ W
// N=100000, E=1600000, D=128.
//
// R3: full counting sort by destination row (100k buckets, avg deg 16), then
// wave-per-row gather with REGISTER accumulation (no LDS, no atomics in the
// hot loop), 4-edge unroll for MLP. R2's fused kernel was latency-bound:
// VALUBusy 3.9%, HBM 4.5%, occupancy 21% -- not enough loads in flight.

#define N_NODES 100000
#define N_EDGES 1600000
#define DIM     128

// ---- workspace layout (bytes) ----
// cnt    @ 0         : 100000 u32  (0.4 MB)
// cursor @ 524288    : 100000 u32  (0.4 MB)
// ebuf   @ 1048576   : E uint2     (12.8 MB)  {col, val_bits} sorted by row
// agg    @ 14680064  : N*128 f32   (51.2 MB)
#define OFF_CURSOR 524288
#define OFF_EBUF   1048576
#define OFF_AGG    14680064

// ---------------------------------------------------------------- zero cnt
__global__ __launch_bounds__(256) void zero_cnt_kernel(unsigned* cnt) {
    int i = blockIdx.x * 256 + threadIdx.x;
    if (i < N_NODES) cnt[i] = 0u;
}

// ---------------------------------------------------------------- histogram
__global__ __launch_bounds__(256) void hist_kernel(
    const int* __restrict__ erow, unsigned* __restrict__ cnt)
{
    int e = blockIdx.x * 256 + threadIdx.x;       // grid exact: E/256
    atomicAdd(&cnt[(unsigned)erow[e]], 1u);
}

// ---------------------------------------------------------------- scan
// exclusive prefix over 100000 counters, single block of 1024 threads,
// 98 contiguous elements per thread. Writes cursor = exclusive start.
#define CHUNK 98
__global__ __launch_bounds__(1024) void scan_kernel(
    const unsigned* __restrict__ cnt, unsigned* __restrict__ cursor)
{
    __shared__ unsigned wsum[16];
    const int t  = threadIdx.x;
    const int i0 = t * CHUNK;
    unsigned s = 0;
    for (int k = 0; k < CHUNK; ++k) {
        int i = i0 + k;
        if (i < N_NODES) s += cnt[i];
    }
    unsigned inc = s;
#pragma unroll
    for (int d = 1; d < 64; d <<= 1) {
        unsigned o = __shfl_up(inc, d);
        if ((t & 63) >= d) inc += o;
    }
    if ((t & 63) == 63) wsum[t >> 6] = inc;
    __syncthreads();
    if (t == 0) {
        unsigned run = 0;
#pragma unroll
        for (int i = 0; i < 16; ++i) { unsigned w = wsum[i]; wsum[i] = run; run += w; }
    }
    __syncthreads();
    unsigned excl = inc - s + wsum[t >> 6];
    for (int k = 0; k < CHUNK; ++k) {
        int i = i0 + k;
        if (i < N_NODES) { cursor[i] = excl; excl += cnt[i]; }
    }
}

// ---------------------------------------------------------------- placement
// after this, cursor[r] == start[r] + deg[r] == end[r]
__global__ __launch_bounds__(256) void place_kernel(
    const int*   __restrict__ erow,
    const int*   __restrict__ ecol,
    const float* __restrict__ eval,
    unsigned*    __restrict__ cursor,
    uint2*       __restrict__ ebuf)
{
    int e = blockIdx.x * 256 + threadIdx.x;       // grid exact
    unsigned r = (unsigned)erow[e];
    unsigned pos = atomicAdd(&cursor[r], 1u);
    ebuf[pos] = make_uint2((unsigned)ecol[e], __float_as_uint(eval[e]));
}

// ---------------------------------------------------------------- aggregate
// one 64-lane wave per dst row; lane owns 2 feature floats in registers.
// Preload <=64 edge records with one coalesced load, broadcast via shfl,
// unroll 4 edges -> 4 independent float2 gathers in flight per lane.
__global__ __launch_bounds__(256) void agg_kernel(
    const float*    __restrict__ x,
    const unsigned* __restrict__ cnt,
    const unsigned* __restrict__ cursor,   // = end
    const uint2*    __restrict__ ebuf,
    float*          __restrict__ agg)
{
    const int lane = threadIdx.x & 63;
    const int row  = blockIdx.x * 4 + (threadIdx.x >> 6);   // grid exact: 25000*4

    const unsigned deg = cnt[row];
    const unsigned s0  = cursor[row] - deg;

    float ax = 0.f, ay = 0.f;

    for (unsigned base = 0; base < deg; base += 64) {
        unsigned rem = deg - base;
        unsigned m   = rem < 64u ? rem : 64u;
        uint2 ev = ((unsigned)lane < m) ? ebuf[s0 + base + lane]
                                        : make_uint2(0u, 0u);
        int   cx = (int)ev.x;
        float vv = __uint_as_float(ev.y);

        unsigned j = 0;
        for (; j + 4 <= m; j += 4) {
            int   c0 = __shfl(cx, (int)j + 0);
            int   c1 = __shfl(cx, (int)j + 1);
            int   c2 = __shfl(cx, (int)j + 2);
            int   c3 = __shfl(cx, (int)j + 3);
            float v0 = __shfl(vv, (int)j + 0);
            float v1 = __shfl(vv, (int)j + 1);
            float v2 = __shfl(vv, (int)j + 2);
            float v3 = __shfl(vv, (int)j + 3);
            float2 f0 = *((const float2*)(x + (size_t)c0 * DIM) + lane);
            float2 f1 = *((const float2*)(x + (size_t)c1 * DIM) + lane);
            float2 f2 = *((const float2*)(x + (size_t)c2 * DIM) + lane);
            float2 f3 = *((const float2*)(x + (size_t)c3 * DIM) + lane);
            ax = fmaf(f0.x, v0, ax); ay = fmaf(f0.y, v0, ay);
            ax = fmaf(f1.x, v1, ax); ay = fmaf(f1.y, v1, ay);
            ax = fmaf(f2.x, v2, ax); ay = fmaf(f2.y, v2, ay);
            ax = fmaf(f3.x, v3, ax); ay = fmaf(f3.y, v3, ay);
        }
        for (; j < m; ++j) {
            int   c = __shfl(cx, (int)j);
            float v = __shfl(vv, (int)j);
            float2 f = *((const float2*)(x + (size_t)c * DIM) + lane);
            ax = fmaf(f.x, v, ax); ay = fmaf(f.y, v, ay);
        }
    }

    *((float2*)(agg + (size_t)row * DIM) + lane) = make_float2(ax, ay);
}

// ---------------------------------------------------------------- GEMM
// out[N,128] = agg[N,128] @ W[128,128] (known-good from R1)
__global__ __launch_bounds__(256) void gemm_kernel(
    const float* __restrict__ agg,
    const float* __restrict__ W,
    float*       __restrict__ out)
{
    __shared__ float As[32 * 32];
    __shared__ float Ws[32 * 128];

    const int t    = threadIdx.x;
    const int row0 = blockIdx.x * 32;          // 3125 blocks exact
    const int r0   = (t >> 5) * 4;
    const int c0   = (t & 31) * 4;

    float acc[4][4];
#pragma unroll
    for (int i = 0; i < 4; ++i)
#pragma unroll
        for (int j = 0; j < 4; ++j) acc[i][j] = 0.f;

    for (int k0 = 0; k0 < 128; k0 += 32) {
        {
            int r  = t >> 3;
            int kp = t & 7;
            float4 a = *(const float4*)(agg + (size_t)(row0 + r) * 128 + k0 + kp * 4);
            *(float4*)(As + r * 32 + kp * 4) = a;
        }
        {
            const float4* Wg = (const float4*)(W + (size_t)k0 * 128);
            float4* Wl = (float4*)Ws;
#pragma unroll
            for (int i = 0; i < 4; ++i) Wl[t + 256 * i] = Wg[t + 256 * i];
        }
        __syncthreads();

#pragma unroll
        for (int kk = 0; kk < 32; ++kk) {
            float4 w = *(const float4*)(Ws + kk * 128 + c0);
            float a0 = As[(r0 + 0) * 32 + kk];
            float a1 = As[(r0 + 1) * 32 + kk];
            float a2 = As[(r0 + 2) * 32 + kk];
            float a3 = As[(r0 + 3) * 32 + kk];
            acc[0][0] += a0 * w.x; acc[0][1] += a0 * w.y; acc[0][2] += a0 * w.z; acc[0][3] += a0 * w.w;
            acc[1][0] += a1 * w.x; acc[1][1] += a1 * w.y; acc[1][2] += a1 * w.z; acc[1][3] += a1 * w.w;
            acc[2][0] += a2 * w.x; acc[2][1] += a2 * w.y; acc[2][2] += a2 * w.z; acc[2][3] += a2 * w.w;
            acc[3][0] += a3 * w.x; acc[3][1] += a3 * w.y; acc[3][2] += a3 * w.z; acc[3][3] += a3 * w.w;
        }
        __syncthreads();
    }

#pragma unroll
    for (int i = 0; i < 4; ++i) {
        float4 o = make_float4(acc[i][0], acc[i][1], acc[i][2], acc[i][3]);
        *(float4*)(out + (size_t)(row0 + r0 + i) * 128 + c0) = o;
    }
}

// ---------------------------------------------------------------- launch
extern "C" void kernel_launch(void* const* d_in, const int* in_sizes, int n_in,
                              void* d_out, int out_size, void* d_ws, size_t ws_size,
                              hipStream_t stream) {
    const float* x    = (const float*)d_in[0];
    const int*   erow = (const int*)d_in[1];
    const int*   ecol = (const int*)d_in[2];
    const float* eval = (const float*)d_in[3];
    const float* W    = (const float*)d_in[4];
    float* out = (float*)d_out;

    char* ws = (char*)d_ws;
    unsigned* cnt    = (unsigned*)(ws);
    unsigned* cursor = (unsigned*)(ws + OFF_CURSOR);
    uint2*    ebuf   = (uint2*)   (ws + OFF_EBUF);
    float*    agg    = (float*)   (ws + OFF_AGG);

    zero_cnt_kernel<<<(N_NODES + 255) / 256, 256, 0, stream>>>(cnt);
    hist_kernel<<<N_EDGES / 256, 256, 0, stream>>>(erow, cnt);
    scan_kernel<<<1, 1024, 0, stream>>>(cnt, cursor);
    place_kernel<<<N_EDGES / 256, 256, 0, stream>>>(erow, ecol, eval, cursor, ebuf);
    agg_kernel<<<N_NODES / 4, 256, 0, stream>>>(x, cnt, cursor, ebuf, agg);
    gemm_kernel<<<N_NODES / 32, 256, 0, stream>>>(agg, W, out);
}

// Round 4
// 408.954 us; speedup vs baseline: 6.8947x; 1.5064x over previous
//
#include <hip/hip_runtime.h>
#include <hip/hip_bf16.h>

// out = segment_sum(x[edge_col] * edge_vals[:,None], edge_row) @ W
// N=100000, E=1600000, D=128.
//
// R4: replace the single-block scan (190 us, 0.17% occupancy -- latency
// bound, was 31% of runtime) with a 2-kernel hierarchical scan.
// Everything else unchanged from R3.

#define N_NODES 100000
#define N_EDGES 1600000
#define DIM     128
#define SCAN_BLOCKS 98        // 98 * 1024 = 100352 >= N_NODES

// ---- workspace layout (bytes) ----
// cnt    @ 0         : 100000 u32  (0.4 MB)
// cursor @ 524288    : 100000 u32  (0.4 MB)
// bsum   @ 1044480   : 98 u32
// ebuf   @ 1048576   : E uint2     (12.8 MB)  {col, val_bits} sorted by row
// agg    @ 14680064  : N*128 f32   (51.2 MB)
#define OFF_CURSOR 524288
#define OFF_BSUM   1044480
#define OFF_EBUF   1048576
#define OFF_AGG    14680064

// ---------------------------------------------------------------- zero cnt
__global__ __launch_bounds__(256) void zero_cnt_kernel(unsigned* cnt) {
    int i = blockIdx.x * 256 + threadIdx.x;
    if (i < N_NODES) cnt[i] = 0u;
}

// ---------------------------------------------------------------- histogram
__global__ __launch_bounds__(256) void hist_kernel(
    const int* __restrict__ erow, unsigned* __restrict__ cnt)
{
    int e = blockIdx.x * 256 + threadIdx.x;       // grid exact: E/256
    atomicAdd(&cnt[(unsigned)erow[e]], 1u);
}

// ---------------------------------------------------------------- scan L1
// 98 blocks x 1024: block-local exclusive scan of cnt -> cursor,
// block total -> bsum[b]
__global__ __launch_bounds__(1024) void scan_blocks_kernel(
    const unsigned* __restrict__ cnt,
    unsigned* __restrict__ cursor,
    unsigned* __restrict__ bsum)
{
    __shared__ unsigned wsum[16];
    const int t = threadIdx.x;
    const int b = blockIdx.x;
    const int i = b * 1024 + t;
    unsigned v = (i < N_NODES) ? cnt[i] : 0u;

    unsigned inc = v;
#pragma unroll
    for (int d = 1; d < 64; d <<= 1) {
        unsigned o = __shfl_up(inc, d);
        if ((t & 63) >= d) inc += o;
    }
    if ((t & 63) == 63) wsum[t >> 6] = inc;
    __syncthreads();
    if (t == 0) {
        unsigned run = 0;
#pragma unroll
        for (int w = 0; w < 16; ++w) { unsigned s = wsum[w]; wsum[w] = run; run += s; }
    }
    __syncthreads();
    unsigned excl = inc - v + wsum[t >> 6];
    if (i < N_NODES) cursor[i] = excl;
    if (t == 1023) bsum[b] = excl + v;
}

// ---------------------------------------------------------------- scan L2
// 98 blocks: wave 0 computes offset = sum(bsum[0..b)), all threads apply.
__global__ __launch_bounds__(1024) void scan_apply_kernel(
    unsigned* __restrict__ cursor, const unsigned* __restrict__ bsum)
{
    __shared__ unsigned off_s;
    const int t = threadIdx.x;
    const int b = blockIdx.x;
    if (t < 64) {
        unsigned s = 0;
        for (int j = t; j < b; j += 64) s += bsum[j];
#pragma unroll
        for (int d = 1; d < 64; d <<= 1) s += __shfl_xor(s, d);
        if (t == 0) off_s = s;
    }
    __syncthreads();
    const unsigned off = off_s;
    const int i = b * 1024 + t;
    if (i < N_NODES && b != 0) cursor[i] += off;
}

// ---------------------------------------------------------------- placement
// after this, cursor[r] == start[r] + deg[r] == end[r]
__global__ __launch_bounds__(256) void place_kernel(
    const int*   __restrict__ erow,
    const int*   __restrict__ ecol,
    const float* __restrict__ eval,
    unsigned*    __restrict__ cursor,
    uint2*       __restrict__ ebuf)
{
    int e = blockIdx.x * 256 + threadIdx.x;       // grid exact
    unsigned r = (unsigned)erow[e];
    unsigned pos = atomicAdd(&cursor[r], 1u);
    ebuf[pos] = make_uint2((unsigned)ecol[e], __float_as_uint(eval[e]));
}

// ---------------------------------------------------------------- aggregate
// one 64-lane wave per dst row; lane owns 2 feature floats in registers.
__global__ __launch_bounds__(256) void agg_kernel(
    const float*    __restrict__ x,
    const unsigned* __restrict__ cnt,
    const unsigned* __restrict__ cursor,   // = end
    const uint2*    __restrict__ ebuf,
    float*          __restrict__ agg)
{
    const int lane = threadIdx.x & 63;
    const int row  = blockIdx.x * 4 + (threadIdx.x >> 6);   // grid exact: 25000*4

    const unsigned deg = cnt[row];
    const unsigned s0  = cursor[row] - deg;

    float ax = 0.f, ay = 0.f;

    for (unsigned base = 0; base < deg; base += 64) {
        unsigned rem = deg - base;
        unsigned m   = rem < 64u ? rem : 64u;
        uint2 ev = ((unsigned)lane < m) ? ebuf[s0 + base + lane]
                                        : make_uint2(0u, 0u);
        int   cx = (int)ev.x;
        float vv = __uint_as_float(ev.y);

        unsigned j = 0;
        for (; j + 4 <= m; j += 4) {
            int   c0 = __shfl(cx, (int)j + 0);
            int   c1 = __shfl(cx, (int)j + 1);
            int   c2 = __shfl(cx, (int)j + 2);
            int   c3 = __shfl(cx, (int)j + 3);
            float v0 = __shfl(vv, (int)j + 0);
            float v1 = __shfl(vv, (int)j + 1);
            float v2 = __shfl(vv, (int)j + 2);
            float v3 = __shfl(vv, (int)j + 3);
            float2 f0 = *((const float2*)(x + (size_t)c0 * DIM) + lane);
            float2 f1 = *((const float2*)(x + (size_t)c1 * DIM) + lane);
            float2 f2 = *((const float2*)(x + (size_t)c2 * DIM) + lane);
            float2 f3 = *((const float2*)(x + (size_t)c3 * DIM) + lane);
            ax = fmaf(f0.x, v0, ax); ay = fmaf(f0.y, v0, ay);
            ax = fmaf(f1.x, v1, ax); ay = fmaf(f1.y, v1, ay);
            ax = fmaf(f2.x, v2, ax); ay = fmaf(f2.y, v2, ay);
            ax = fmaf(f3.x, v3, ax); ay = fmaf(f3.y, v3, ay);
        }
        for (; j < m; ++j) {
            int   c = __shfl(cx, (int)j);
            float v = __shfl(vv, (int)j);
            float2 f = *((const float2*)(x + (size_t)c * DIM) + lane);
            ax = fmaf(f.x, v, ax); ay = fmaf(f.y, v, ay);
        }
    }

    *((float2*)(agg + (size_t)row * DIM) + lane) = make_float2(ax, ay);
}

// ---------------------------------------------------------------- GEMM
__global__ __launch_bounds__(256) void gemm_kernel(
    const float* __restrict__ agg,
    const float* __restrict__ W,
    float*       __restrict__ out)
{
    __shared__ float As[32 * 32];
    __shared__ float Ws[32 * 128];

    const int t    = threadIdx.x;
    const int row0 = blockIdx.x * 32;          // 3125 blocks exact
    const int r0   = (t >> 5) * 4;
    const int c0   = (t & 31) * 4;

    float acc[4][4];
#pragma unroll
    for (int i = 0; i < 4; ++i)
#pragma unroll
        for (int j = 0; j < 4; ++j) acc[i][j] = 0.f;

    for (int k0 = 0; k0 < 128; k0 += 32) {
        {
            int r  = t >> 3;
            int kp = t & 7;
            float4 a = *(const float4*)(agg + (size_t)(row0 + r) * 128 + k0 + kp * 4);
            *(float4*)(As + r * 32 + kp * 4) = a;
        }
        {
            const float4* Wg = (const float4*)(W + (size_t)k0 * 128);
            float4* Wl = (float4*)Ws;
#pragma unroll
            for (int i = 0; i < 4; ++i) Wl[t + 256 * i] = Wg[t + 256 * i];
        }
        __syncthreads();

#pragma unroll
        for (int kk = 0; kk < 32; ++kk) {
            float4 w = *(const float4*)(Ws + kk * 128 + c0);
            float a0 = As[(r0 + 0) * 32 + kk];
            float a1 = As[(r0 + 1) * 32 + kk];
            float a2 = As[(r0 + 2) * 32 + kk];
            float a3 = As[(r0 + 3) * 32 + kk];
            acc[0][0] += a0 * w.x; acc[0][1] += a0 * w.y; acc[0][2] += a0 * w.z; acc[0][3] += a0 * w.w;
            acc[1][0] += a1 * w.x; acc[1][1] += a1 * w.y; acc[1][2] += a1 * w.z; acc[1][3] += a1 * w.w;
            acc[2][0] += a2 * w.x; acc[2][1] += a2 * w.y; acc[2][2] += a2 * w.z; acc[2][3] += a2 * w.w;
            acc[3][0] += a3 * w.x; acc[3][1] += a3 * w.y; acc[3][2] += a3 * w.z; acc[3][3] += a3 * w.w;
        }
        __syncthreads();
    }

#pragma unroll
    for (int i = 0; i < 4; ++i) {
        float4 o = make_float4(acc[i][0], acc[i][1], acc[i][2], acc[i][3]);
        *(float4*)(out + (size_t)(row0 + r0 + i) * 128 + c0) = o;
    }
}

// ---------------------------------------------------------------- launch
extern "C" void kernel_launch(void* const* d_in, const int* in_sizes, int n_in,
                              void* d_out, int out_size, void* d_ws, size_t ws_size,
                              hipStream_t stream) {
    const float* x    = (const float*)d_in[0];
    const int*   erow = (const int*)d_in[1];
    const int*   ecol = (const int*)d_in[2];
    const float* eval = (const float*)d_in[3];
    const float* W    = (const float*)d_in[4];
    float* out = (float*)d_out;

    char* ws = (char*)d_ws;
    unsigned* cnt    = (unsigned*)(ws);
    unsigned* cursor = (unsigned*)(ws + OFF_CURSOR);
    unsigned* bsum   = (unsigned*)(ws + OFF_BSUM);
    uint2*    ebuf   = (uint2*)   (ws + OFF_EBUF);
    float*    agg    = (float*)   (ws + OFF_AGG);

    zero_cnt_kernel<<<(N_NODES + 255) / 256, 256, 0, stream>>>(cnt);
    hist_kernel<<<N_EDGES / 256, 256, 0, stream>>>(erow, cnt);
    scan_blocks_kernel<<<SCAN_BLOCKS, 1024, 0, stream>>>(cnt, cursor, bsum);
    scan_apply_kernel<<<SCAN_BLOCKS, 1024, 0, stream>>>(cursor, bsum);
    place_kernel<<<N_EDGES / 256, 256, 0, stream>>>(erow, ecol, eval, cursor, ebuf);
    agg_kernel<<<N_NODES / 4, 256, 0, stream>>>(x, cnt, cursor, ebuf, agg);
    gemm_kernel<<<N_NODES / 32, 256, 0, stream>>>(agg, W, out);
}

// Round 5
// 407.310 us; speedup vs baseline: 6.9225x; 1.0040x over previous
//
#include <hip/hip_runtime.h>
#include <hip/hip_bf16.h>

// out = segment_sum(x[edge_col] * edge_vals[:,None], edge_row) @ W
// N=100000, E=1600000, D=128.
//
// R5: replace single-pass placement (120 us; WRITE_SIZE 100 MB for a 12.8 MB
// buffer = partial-line write-through on random 8 B writes) with a two-pass
// partition: coarse LDS-histogram partition into 391 buckets of 256 rows
// (runs of ~21 contiguous records), then per-bucket finalize whose writes all
// land in one 32 KB L2-resident window owned by a single block.
// hist/scan/agg/gemm unchanged from R4.

#define N_NODES 100000
#define N_EDGES 1600000
#define DIM     128
#define SCAN_BLOCKS 98        // 98 * 1024 = 100352 >= N_NODES
#define CB  391               // coarse buckets = ceil(N_NODES / 256)
#define CBW 256               // rows per coarse bucket (rowLocal fits 8 bits)

// ---- workspace layout (bytes) ----  (peak 65.2 MB, <= R4's proven 65.9 MB)
// cnt    @ 0          : 100000 u32
// cursor @ 524288     : 100000 u32
// bsum   @ 1000000    : 98 u32
// cstart @ 1001472    : 391 u32   (coarse bucket start = start[b*256])
// ccur   @ 1003520    : 391 u32   (partition cursors)
// ebuf   @ 1048576    : E uint2 {col, val}   [finalize -> agg]
// ebuf1  @ 14000000   : E uint2 {rowLocal<<17|col, val}  [partition -> finalize]
// agg    @ 14000000   : N*128 f32  (OVERLAPS ebuf1; ebuf1 dead before agg write)
#define OFF_CURSOR 524288
#define OFF_BSUM   1000000
#define OFF_CSTART 1001472
#define OFF_CCUR   1003520
#define OFF_EBUF   1048576
#define OFF_EBUF1  14000000
#define OFF_AGG    14000000

// ---------------------------------------------------------------- zero cnt
__global__ __launch_bounds__(256) void zero_cnt_kernel(unsigned* cnt) {
    int i = blockIdx.x * 256 + threadIdx.x;
    if (i < N_NODES) cnt[i] = 0u;
}

// ---------------------------------------------------------------- histogram
__global__ __launch_bounds__(256) void hist_kernel(
    const int* __restrict__ erow, unsigned* __restrict__ cnt)
{
    int e = blockIdx.x * 256 + threadIdx.x;       // grid exact: E/256
    atomicAdd(&cnt[(unsigned)erow[e]], 1u);
}

// ---------------------------------------------------------------- scan L1
__global__ __launch_bounds__(1024) void scan_blocks_kernel(
    const unsigned* __restrict__ cnt,
    unsigned* __restrict__ cursor,
    unsigned* __restrict__ bsum)
{
    __shared__ unsigned wsum[16];
    const int t = threadIdx.x;
    const int b = blockIdx.x;
    const int i = b * 1024 + t;
    unsigned v = (i < N_NODES) ? cnt[i] : 0u;

    unsigned inc = v;
#pragma unroll
    for (int d = 1; d < 64; d <<= 1) {
        unsigned o = __shfl_up(inc, d);
        if ((t & 63) >= d) inc += o;
    }
    if ((t & 63) == 63) wsum[t >> 6] = inc;
    __syncthreads();
    if (t == 0) {
        unsigned run = 0;
#pragma unroll
        for (int w = 0; w < 16; ++w) { unsigned s = wsum[w]; wsum[w] = run; run += s; }
    }
    __syncthreads();
    unsigned excl = inc - v + wsum[t >> 6];
    if (i < N_NODES) cursor[i] = excl;
    if (t == 1023) bsum[b] = excl + v;
}

// ---------------------------------------------------------------- scan L2
__global__ __launch_bounds__(1024) void scan_apply_kernel(
    unsigned* __restrict__ cursor, const unsigned* __restrict__ bsum)
{
    __shared__ unsigned off_s;
    const int t = threadIdx.x;
    const int b = blockIdx.x;
    if (t < 64) {
        unsigned s = 0;
        for (int j = t; j < b; j += 64) s += bsum[j];
#pragma unroll
        for (int d = 1; d < 64; d <<= 1) s += __shfl_xor(s, d);
        if (t == 0) off_s = s;
    }
    __syncthreads();
    const unsigned off = off_s;
    const int i = b * 1024 + t;
    if (i < N_NODES && b != 0) cursor[i] += off;
}

// ---------------------------------------------------------------- prep
// cstart[b] = start of coarse bucket b in ebuf; ccur[b] = running cursor
__global__ __launch_bounds__(256) void prep_kernel(
    const unsigned* __restrict__ cursor,
    unsigned* __restrict__ cstart,
    unsigned* __restrict__ ccur)
{
    int b = blockIdx.x * 256 + threadIdx.x;
    if (b < CB) {
        unsigned s = cursor[b * CBW];
        cstart[b] = s;
        ccur[b]   = s;
    }
}

// ---------------------------------------------------------------- partition
// pass 1: chunk of 8192 edges per block; LDS hist over 391 coarse buckets,
// reserve global space per bucket, scatter records in per-bucket runs.
__global__ __launch_bounds__(256) void partition_kernel(
    const int*   __restrict__ erow,
    const int*   __restrict__ ecol,
    const float* __restrict__ eval,
    unsigned*    __restrict__ ccur,
    uint2*       __restrict__ ebuf1)
{
    __shared__ unsigned hist[CB];
    __shared__ unsigned gbase[CB];
    const int t = threadIdx.x;
    const unsigned e0 = blockIdx.x * 8192u;      // grid: 196 blocks

    for (int i = t; i < CB; i += 256) hist[i] = 0u;
    __syncthreads();

#pragma unroll 4
    for (int k = 0; k < 32; ++k) {
        unsigned e = e0 + k * 256u + t;
        if (e < N_EDGES) atomicAdd(&hist[(unsigned)erow[e] >> 8], 1u);
    }
    __syncthreads();

    for (int i = t; i < CB; i += 256) {
        unsigned h = hist[i];
        gbase[i] = h ? atomicAdd(&ccur[i], h) : 0u;
        hist[i] = 0u;                            // reuse as local rank counter
    }
    __syncthreads();

#pragma unroll 4
    for (int k = 0; k < 32; ++k) {
        unsigned e = e0 + k * 256u + t;
        if (e < N_EDGES) {
            unsigned r = (unsigned)erow[e];
            unsigned b = r >> 8;
            unsigned rank = atomicAdd(&hist[b], 1u);
            ebuf1[gbase[b] + rank] =
                make_uint2(((r & 255u) << 17) | (unsigned)ecol[e],
                           __float_as_uint(eval[e]));
        }
    }
}

// ---------------------------------------------------------------- finalize
// pass 2: one block per coarse bucket; all writes land in a 32 KB window
// owned by this block -> L2 lines fill completely.
// After this, cursor[r] == end[r] (as agg expects).
__global__ __launch_bounds__(256) void finalize_kernel(
    const unsigned* __restrict__ cstart,
    unsigned*       __restrict__ cursor,
    const uint2*    __restrict__ ebuf1,
    uint2*          __restrict__ ebuf)
{
    const int b = blockIdx.x;                    // grid: CB blocks
    const unsigned lo = cstart[b];
    const unsigned hi = (b == CB - 1) ? (unsigned)N_EDGES : cstart[b + 1];
    for (unsigned i = lo + threadIdx.x; i < hi; i += 256) {
        uint2 rec = ebuf1[i];
        unsigned r = ((unsigned)b << 8) + (rec.x >> 17);
        unsigned pos = atomicAdd(&cursor[r], 1u);
        ebuf[pos] = make_uint2(rec.x & 0x1FFFFu, rec.y);
    }
}

// ---------------------------------------------------------------- aggregate
// one 64-lane wave per dst row; lane owns 2 feature floats in registers.
__global__ __launch_bounds__(256) void agg_kernel(
    const float*    __restrict__ x,
    const unsigned* __restrict__ cnt,
    const unsigned* __restrict__ cursor,   // = end
    const uint2*    __restrict__ ebuf,
    float*          __restrict__ agg)
{
    const int lane = threadIdx.x & 63;
    const int row  = blockIdx.x * 4 + (threadIdx.x >> 6);   // grid exact: 25000*4

    const unsigned deg = cnt[row];
    const unsigned s0  = cursor[row] - deg;

    float ax = 0.f, ay = 0.f;

    for (unsigned base = 0; base < deg; base += 64) {
        unsigned rem = deg - base;
        unsigned m   = rem < 64u ? rem : 64u;
        uint2 ev = ((unsigned)lane < m) ? ebuf[s0 + base + lane]
                                        : make_uint2(0u, 0u);
        int   cx = (int)ev.x;
        float vv = __uint_as_float(ev.y);

        unsigned j = 0;
        for (; j + 4 <= m; j += 4) {
            int   c0 = __shfl(cx, (int)j + 0);
            int   c1 = __shfl(cx, (int)j + 1);
            int   c2 = __shfl(cx, (int)j + 2);
            int   c3 = __shfl(cx, (int)j + 3);
            float v0 = __shfl(vv, (int)j + 0);
            float v1 = __shfl(vv, (int)j + 1);
            float v2 = __shfl(vv, (int)j + 2);
            float v3 = __shfl(vv, (int)j + 3);
            float2 f0 = *((const float2*)(x + (size_t)c0 * DIM) + lane);
            float2 f1 = *((const float2*)(x + (size_t)c1 * DIM) + lane);
            float2 f2 = *((const float2*)(x + (size_t)c2 * DIM) + lane);
            float2 f3 = *((const float2*)(x + (size_t)c3 * DIM) + lane);
            ax = fmaf(f0.x, v0, ax); ay = fmaf(f0.y, v0, ay);
            ax = fmaf(f1.x, v1, ax); ay = fmaf(f1.y, v1, ay);
            ax = fmaf(f2.x, v2, ax); ay = fmaf(f2.y, v2, ay);
            ax = fmaf(f3.x, v3, ax); ay = fmaf(f3.y, v3, ay);
        }
        for (; j < m; ++j) {
            int   c = __shfl(cx, (int)j);
            float v = __shfl(vv, (int)j);
            float2 f = *((const float2*)(x + (size_t)c * DIM) + lane);
            ax = fmaf(f.x, v, ax); ay = fmaf(f.y, v, ay);
        }
    }

    *((float2*)(agg + (size_t)row * DIM) + lane) = make_float2(ax, ay);
}

// ---------------------------------------------------------------- GEMM
__global__ __launch_bounds__(256) void gemm_kernel(
    const float* __restrict__ agg,
    const float* __restrict__ W,
    float*       __restrict__ out)
{
    __shared__ float As[32 * 32];
    __shared__ float Ws[32 * 128];

    const int t    = threadIdx.x;
    const int row0 = blockIdx.x * 32;          // 3125 blocks exact
    const int r0   = (t >> 5) * 4;
    const int c0   = (t & 31) * 4;

    float acc[4][4];
#pragma unroll
    for (int i = 0; i < 4; ++i)
#pragma unroll
        for (int j = 0; j < 4; ++j) acc[i][j] = 0.f;

    for (int k0 = 0; k0 < 128; k0 += 32) {
        {
            int r  = t >> 3;
            int kp = t & 7;
            float4 a = *(const float4*)(agg + (size_t)(row0 + r) * 128 + k0 + kp * 4);
            *(float4*)(As + r * 32 + kp * 4) = a;
        }
        {
            const float4* Wg = (const float4*)(W + (size_t)k0 * 128);
            float4* Wl = (float4*)Ws;
#pragma unroll
            for (int i = 0; i < 4; ++i) Wl[t + 256 * i] = Wg[t + 256 * i];
        }
        __syncthreads();

#pragma unroll
        for (int kk = 0; kk < 32; ++kk) {
            float4 w = *(const float4*)(Ws + kk * 128 + c0);
            float a0 = As[(r0 + 0) * 32 + kk];
            float a1 = As[(r0 + 1) * 32 + kk];
            float a2 = As[(r0 + 2) * 32 + kk];
            float a3 = As[(r0 + 3) * 32 + kk];
            acc[0][0] += a0 * w.x; acc[0][1] += a0 * w.y; acc[0][2] += a0 * w.z; acc[0][3] += a0 * w.w;
            acc[1][0] += a1 * w.x; acc[1][1] += a1 * w.y; acc[1][2] += a1 * w.z; acc[1][3] += a1 * w.w;
            acc[2][0] += a2 * w.x; acc[2][1] += a2 * w.y; acc[2][2] += a2 * w.z; acc[2][3] += a2 * w.w;
            acc[3][0] += a3 * w.x; acc[3][1] += a3 * w.y; acc[3][2] += a3 * w.z; acc[3][3] += a3 * w.w;
        }
        __syncthreads();
    }

#pragma unroll
    for (int i = 0; i < 4; ++i) {
        float4 o = make_float4(acc[i][0], acc[i][1], acc[i][2], acc[i][3]);
        *(float4*)(out + (size_t)(row0 + r0 + i) * 128 + c0) = o;
    }
}

// ---------------------------------------------------------------- launch
extern "C" void kernel_launch(void* const* d_in, const int* in_sizes, int n_in,
                              void* d_out, int out_size, void* d_ws, size_t ws_size,
                              hipStream_t stream) {
    const float* x    = (const float*)d_in[0];
    const int*   erow = (const int*)d_in[1];
    const int*   ecol = (const int*)d_in[2];
    const float* eval = (const float*)d_in[3];
    const float* W    = (const float*)d_in[4];
    float* out = (float*)d_out;

    char* ws = (char*)d_ws;
    unsigned* cnt    = (unsigned*)(ws);
    unsigned* cursor = (unsigned*)(ws + OFF_CURSOR);
    unsigned* bsum   = (unsigned*)(ws + OFF_BSUM);
    unsigned* cstart = (unsigned*)(ws + OFF_CSTART);
    unsigned* ccur   = (unsigned*)(ws + OFF_CCUR);
    uint2*    ebuf   = (uint2*)   (ws + OFF_EBUF);
    uint2*    ebuf1  = (uint2*)   (ws + OFF_EBUF1);
    float*    agg    = (float*)   (ws + OFF_AGG);   // overlaps ebuf1 (disjoint lifetime)

    zero_cnt_kernel<<<(N_NODES + 255) / 256, 256, 0, stream>>>(cnt);
    hist_kernel<<<N_EDGES / 256, 256, 0, stream>>>(erow, cnt);
    scan_blocks_kernel<<<SCAN_BLOCKS, 1024, 0, stream>>>(cnt, cursor, bsum);
    scan_apply_kernel<<<SCAN_BLOCKS, 1024, 0, stream>>>(cursor, bsum);
    prep_kernel<<<(CB + 255) / 256, 256, 0, stream>>>(cursor, cstart, ccur);
    partition_kernel<<<196, 256, 0, stream>>>(erow, ecol, eval, ccur, ebuf1);
    finalize_kernel<<<CB, 256, 0, stream>>>(cstart, cursor, ebuf1, ebuf);
    agg_kernel<<<N_NODES / 4, 256, 0, stream>>>(x, cnt, cursor, ebuf, agg);
    gemm_kernel<<<N_NODES / 32, 256, 0, stream>>>(agg, W, out);
}

// Round 6
// 299.890 us; speedup vs baseline: 9.4021x; 1.3582x over previous
//
#include <hip/hip_runtime.h>
#include <hip/hip_fp16.h>

// out = segment_sum(x[edge_col] * edge_vals[:,None], edge_row) @ W
// N=100000, E=1600000, D=128.
//
// R6: (A·X)·W -> A·(X·W). GEMM first into fp16 y (halves gather bytes),
// then coarse counting-sort (782 buckets x 128 rows) + fused per-bucket
// LDS-sort + register-gather kernel writing out directly.
// R5 spent ~200us on sort infra and agg gathered fp32 (512 B/row);
// this gathers fp16 (256 B/row) and deletes hist100k/scan100k/prep/
// finalize/ebuf/agg entirely (9 kernels -> 6).

#define N_NODES 100000
#define N_EDGES 1600000
#define DIM     128
#define CB      782          // coarse buckets = ceil(N/128)
#define CAP     3072         // LDS sort capacity per chunk (mean bucket=2048, sigma~45)

// ---- workspace layout (bytes) ----
// y     @ 0        : N*128 fp16 = 25.6 MB
// ccnt  @ 25600000 : 782 u32
// cstart@ 25603200 : 783 u32
// ccur  @ 25606400 : 782 u32
// ebuf1 @ 25610240 : E uint2 {rl<<17|col, val_bits} = 12.8 MB   (peak 38.4 MB)
#define OFF_CCNT   25600000
#define OFF_CSTART 25603200
#define OFF_CCUR   25606400
#define OFF_EBUF1  25610240

// ---------------------------------------------------------------- GEMM x@W -> y (fp16)
__global__ __launch_bounds__(256) void gemm_xw_kernel(
    const float* __restrict__ x,
    const float* __restrict__ W,
    __half*      __restrict__ y)
{
    __shared__ float As[32 * 32];
    __shared__ float Ws[32 * 128];

    const int t    = threadIdx.x;
    const int row0 = blockIdx.x * 32;          // 3125 blocks exact
    const int r0   = (t >> 5) * 4;
    const int c0   = (t & 31) * 4;

    float acc[4][4];
#pragma unroll
    for (int i = 0; i < 4; ++i)
#pragma unroll
        for (int j = 0; j < 4; ++j) acc[i][j] = 0.f;

    for (int k0 = 0; k0 < 128; k0 += 32) {
        {
            int r  = t >> 3;
            int kp = t & 7;
            float4 a = *(const float4*)(x + (size_t)(row0 + r) * 128 + k0 + kp * 4);
            *(float4*)(As + r * 32 + kp * 4) = a;
        }
        {
            const float4* Wg = (const float4*)(W + (size_t)k0 * 128);
            float4* Wl = (float4*)Ws;
#pragma unroll
            for (int i = 0; i < 4; ++i) Wl[t + 256 * i] = Wg[t + 256 * i];
        }
        __syncthreads();

#pragma unroll
        for (int kk = 0; kk < 32; ++kk) {
            float4 w = *(const float4*)(Ws + kk * 128 + c0);
            float a0 = As[(r0 + 0) * 32 + kk];
            float a1 = As[(r0 + 1) * 32 + kk];
            float a2 = As[(r0 + 2) * 32 + kk];
            float a3 = As[(r0 + 3) * 32 + kk];
            acc[0][0] += a0 * w.x; acc[0][1] += a0 * w.y; acc[0][2] += a0 * w.z; acc[0][3] += a0 * w.w;
            acc[1][0] += a1 * w.x; acc[1][1] += a1 * w.y; acc[1][2] += a1 * w.z; acc[1][3] += a1 * w.w;
            acc[2][0] += a2 * w.x; acc[2][1] += a2 * w.y; acc[2][2] += a2 * w.z; acc[2][3] += a2 * w.w;
            acc[3][0] += a3 * w.x; acc[3][1] += a3 * w.y; acc[3][2] += a3 * w.z; acc[3][3] += a3 * w.w;
        }
        __syncthreads();
    }

#pragma unroll
    for (int i = 0; i < 4; ++i) {
        __half2 p0 = __floats2half2_rn(acc[i][0], acc[i][1]);
        __half2 p1 = __floats2half2_rn(acc[i][2], acc[i][3]);
        uint2 w;
        w.x = *(const unsigned*)&p0;
        w.y = *(const unsigned*)&p1;
        *(uint2*)(y + (size_t)(row0 + r0 + i) * 128 + c0) = w;
    }
}

// ---------------------------------------------------------------- zero coarse cnt
__global__ __launch_bounds__(256) void zero_ccnt_kernel(unsigned* ccnt) {
    int i = blockIdx.x * 256 + threadIdx.x;
    if (i < CB) ccnt[i] = 0u;
}

// ---------------------------------------------------------------- coarse hist
__global__ __launch_bounds__(256) void coarse_hist_kernel(
    const int* __restrict__ erow, unsigned* __restrict__ ccnt)
{
    __shared__ unsigned lh[CB];
    const int t = threadIdx.x;
    const unsigned e0 = blockIdx.x * 8192u;      // 196 blocks
    for (int i = t; i < CB; i += 256) lh[i] = 0u;
    __syncthreads();
#pragma unroll 4
    for (int k = 0; k < 32; ++k) {
        unsigned e = e0 + k * 256u + t;
        if (e < N_EDGES) atomicAdd(&lh[(unsigned)erow[e] >> 7], 1u);
    }
    __syncthreads();
    for (int i = t; i < CB; i += 256) {
        unsigned h = lh[i];
        if (h) atomicAdd(&ccnt[i], h);
    }
}

// ---------------------------------------------------------------- coarse scan
// single block of 1024: exclusive scan of 782 counters -> cstart[0..782], ccur
__global__ __launch_bounds__(1024) void coarse_scan_kernel(
    const unsigned* __restrict__ ccnt,
    unsigned* __restrict__ cstart,
    unsigned* __restrict__ ccur)
{
    __shared__ unsigned wsum[16];
    const int t = threadIdx.x;
    unsigned v = (t < CB) ? ccnt[t] : 0u;
    unsigned inc = v;
#pragma unroll
    for (int d = 1; d < 64; d <<= 1) {
        unsigned o = __shfl_up(inc, d);
        if ((t & 63) >= d) inc += o;
    }
    if ((t & 63) == 63) wsum[t >> 6] = inc;
    __syncthreads();
    if (t == 0) {
        unsigned run = 0;
#pragma unroll
        for (int w = 0; w < 16; ++w) { unsigned s = wsum[w]; wsum[w] = run; run += s; }
    }
    __syncthreads();
    unsigned excl = inc - v + wsum[t >> 6];
    if (t <= CB) cstart[t] = excl;   // cstart[CB] == E
    if (t <  CB) ccur[t]   = excl;
}

// ---------------------------------------------------------------- partition
// LDS hist over 782 buckets per 8192-edge chunk, reserve, scatter runs.
// record: {rowLocal(7b)<<17 | col(17b), val_bits}
__global__ __launch_bounds__(256) void partition_kernel(
    const int*   __restrict__ erow,
    const int*   __restrict__ ecol,
    const float* __restrict__ eval,
    unsigned*    __restrict__ ccur,
    uint2*       __restrict__ ebuf1)
{
    __shared__ unsigned hist[CB];
    __shared__ unsigned gbase[CB];
    const int t = threadIdx.x;
    const unsigned e0 = blockIdx.x * 8192u;      // 196 blocks

    for (int i = t; i < CB; i += 256) hist[i] = 0u;
    __syncthreads();

#pragma unroll 4
    for (int k = 0; k < 32; ++k) {
        unsigned e = e0 + k * 256u + t;
        if (e < N_EDGES) atomicAdd(&hist[(unsigned)erow[e] >> 7], 1u);
    }
    __syncthreads();

    for (int i = t; i < CB; i += 256) {
        unsigned h = hist[i];
        gbase[i] = h ? atomicAdd(&ccur[i], h) : 0u;
        hist[i] = 0u;                            // reuse as local rank counter
    }
    __syncthreads();

#pragma unroll 4
    for (int k = 0; k < 32; ++k) {
        unsigned e = e0 + k * 256u + t;
        if (e < N_EDGES) {
            unsigned r = (unsigned)erow[e];
            unsigned b = r >> 7;
            unsigned rank = atomicAdd(&hist[b], 1u);
            ebuf1[gbase[b] + rank] =
                make_uint2(((r & 127u) << 17) | (unsigned)ecol[e],
                           __float_as_uint(eval[e]));
        }
    }
}

// ---------------------------------------------------------------- bucket agg
// one block per coarse bucket: counting-sort its slice by row in LDS, then
// wave-per-row register gather of fp16 y rows, write out fp32 directly.
__global__ __launch_bounds__(256) void bucket_agg_kernel(
    const __half*   __restrict__ y,
    const unsigned* __restrict__ cstart,
    const uint2*    __restrict__ ebuf1,
    float*          __restrict__ out)
{
    __shared__ uint2    sorted[CAP];     // 24 KB
    __shared__ unsigned hist[128];
    __shared__ unsigned sstart[128];
    __shared__ unsigned scur[128];

    const int t    = threadIdx.x;
    const int b    = blockIdx.x;                 // 782 blocks
    const int lane = t & 63;
    const int wv   = t >> 6;
    const unsigned lo = cstart[b];
    const unsigned hi = cstart[b + 1];
    const unsigned n  = hi - lo;
    const unsigned nchunks = n ? (n + CAP - 1) / CAP : 1u;

    for (unsigned c = 0; c < nchunks; ++c) {
        const unsigned base = lo + c * CAP;
        const unsigned m = (base < hi) ? ((hi - base < CAP) ? hi - base : CAP) : 0u;

        for (int i = t; i < 128; i += 256) { }   // (128<256: single step below)
        if (t < 128) hist[t] = 0u;
        __syncthreads();

        for (unsigned i = t; i < m; i += 256)
            atomicAdd(&hist[ebuf1[base + i].x >> 17], 1u);
        __syncthreads();

        if (t < 64) {                            // scan 128 counters, wave 0
            unsigned a  = hist[2 * t];
            unsigned bb = hist[2 * t + 1];
            unsigned s  = a + bb;
            unsigned inc = s;
#pragma unroll
            for (int d = 1; d < 64; d <<= 1) {
                unsigned o = __shfl_up(inc, d);
                if (t >= d) inc += o;
            }
            unsigned excl = inc - s;
            sstart[2 * t]     = excl;     scur[2 * t]     = excl;
            sstart[2 * t + 1] = excl + a; scur[2 * t + 1] = excl + a;
        }
        __syncthreads();

        for (unsigned i = t; i < m; i += 256) {
            uint2 rec = ebuf1[base + i];
            unsigned p = atomicAdd(&scur[rec.x >> 17], 1u);
            sorted[p] = rec;
        }
        __syncthreads();

        for (int r = wv; r < 128; r += 4) {
            int row = b * 128 + r;
            if (row >= N_NODES) break;
            float ax, ay;
            if (c == 0) { ax = 0.f; ay = 0.f; }
            else {
                float2 p = *((const float2*)(out + (size_t)row * 128) + lane);
                ax = p.x; ay = p.y;
            }
            unsigned j = sstart[r], e = scur[r];
            for (; j + 4 <= e; j += 4) {
                uint2 r0 = sorted[j + 0];
                uint2 r1 = sorted[j + 1];
                uint2 r2 = sorted[j + 2];
                uint2 r3 = sorted[j + 3];
                const __half2 h0 = *((const __half2*)(y + (size_t)(r0.x & 0x1FFFFu) * 128) + lane);
                const __half2 h1 = *((const __half2*)(y + (size_t)(r1.x & 0x1FFFFu) * 128) + lane);
                const __half2 h2 = *((const __half2*)(y + (size_t)(r2.x & 0x1FFFFu) * 128) + lane);
                const __half2 h3 = *((const __half2*)(y + (size_t)(r3.x & 0x1FFFFu) * 128) + lane);
                float v0 = __uint_as_float(r0.y);
                float v1 = __uint_as_float(r1.y);
                float v2 = __uint_as_float(r2.y);
                float v3 = __uint_as_float(r3.y);
                float2 f0 = __half22float2(h0);
                float2 f1 = __half22float2(h1);
                float2 f2 = __half22float2(h2);
                float2 f3 = __half22float2(h3);
                ax = fmaf(f0.x, v0, ax); ay = fmaf(f0.y, v0, ay);
                ax = fmaf(f1.x, v1, ax); ay = fmaf(f1.y, v1, ay);
                ax = fmaf(f2.x, v2, ax); ay = fmaf(f2.y, v2, ay);
                ax = fmaf(f3.x, v3, ax); ay = fmaf(f3.y, v3, ay);
            }
            for (; j < e; ++j) {
                uint2 rr = sorted[j];
                const __half2 h = *((const __half2*)(y + (size_t)(rr.x & 0x1FFFFu) * 128) + lane);
                float v = __uint_as_float(rr.y);
                float2 f = __half22float2(h);
                ax = fmaf(f.x, v, ax); ay = fmaf(f.y, v, ay);
            }
            *((float2*)(out + (size_t)row * 128) + lane) = make_float2(ax, ay);
        }
        __syncthreads();
    }
}

// ---------------------------------------------------------------- launch
extern "C" void kernel_launch(void* const* d_in, const int* in_sizes, int n_in,
                              void* d_out, int out_size, void* d_ws, size_t ws_size,
                              hipStream_t stream) {
    const float* x    = (const float*)d_in[0];
    const int*   erow = (const int*)d_in[1];
    const int*   ecol = (const int*)d_in[2];
    const float* eval = (const float*)d_in[3];
    const float* W    = (const float*)d_in[4];
    float* out = (float*)d_out;

    char* ws = (char*)d_ws;
    __half*   y      = (__half*)  (ws);
    unsigned* ccnt   = (unsigned*)(ws + OFF_CCNT);
    unsigned* cstart = (unsigned*)(ws + OFF_CSTART);
    unsigned* ccur   = (unsigned*)(ws + OFF_CCUR);
    uint2*    ebuf1  = (uint2*)   (ws + OFF_EBUF1);

    gemm_xw_kernel<<<N_NODES / 32, 256, 0, stream>>>(x, W, y);
    zero_ccnt_kernel<<<(CB + 255) / 256, 256, 0, stream>>>(ccnt);
    coarse_hist_kernel<<<196, 256, 0, stream>>>(erow, ccnt);
    coarse_scan_kernel<<<1, 1024, 0, stream>>>(ccnt, cstart, ccur);
    partition_kernel<<<196, 256, 0, stream>>>(erow, ecol, eval, ccur, ebuf1);
    bucket_agg_kernel<<<CB, 256, 0, stream>>>(y, cstart, ebuf1, out);
}